// Round 3
// baseline (2727.339 us; speedup 1.0000x reference)
//
#include <hip/hip_runtime.h>
#include <stdint.h>
#include <stddef.h>

typedef _Float16 f16;
typedef f16 f16x8 __attribute__((ext_vector_type(8)));
typedef float f32x4 __attribute__((ext_vector_type(4)));

#define STRIDE 616          // LDS row stride (f16 elems): 1232 B
#define BATCH 131072

// Per-layer dims: (o, k); kpad = align32(k); opad = align128(o)
static constexpr int  LO[10]  = {600,600,160,600,600,379,40,40,40,2};
static constexpr int  LK[10]  = {379,600,600,80,600,600,160,40,40,40};
static constexpr int  LKP[10] = {384,608,608,96,608,608,160,64,64,64};
static constexpr int  LOPD[10]= {640,640,256,640,640,384,128,128,128,128};
static constexpr long WOFF[11] = {0,245760,634880,790528,851968,1241088,1474560,1495040,1503232,1511424,1519616};
#define WTOTAL 1519616      // f16 elems (~2.9 MB in d_ws)

// ---------------------------------------------------------------------------
// NOTE: harness delivers ALL integer inputs as int32 ("integer -> const int*").
// int32 [o][k] -> f16 padded [opad][kpad] (exact integer values; scale+bias in epilogue)
// ---------------------------------------------------------------------------
struct ConvArgs { const int* w[10]; f16* dst; };

__global__ __launch_bounds__(256) void convert_weights(ConvArgs a) {
  long e8 = ((long)blockIdx.x * 256 + threadIdx.x) * 8;
#pragma unroll
  for (int l = 0; l < 10; ++l) {
    if (e8 >= WOFF[l] && e8 < WOFF[l + 1]) {
      int local = (int)(e8 - WOFF[l]);
      int o  = local / LKP[l];
      int k0 = local - o * LKP[l];
      const int* w = a.w[l];
      f16 v8[8];
#pragma unroll
      for (int j = 0; j < 8; ++j) {
        int k = k0 + j;
        int iv = (o < LO[l] && k < LK[l]) ? w[o * LK[l] + k] : 0;
        v8[j] = (f16)(float)iv;
      }
      *(f16x8*)(a.dst + e8) = *(const f16x8*)v8;
    }
  }
}

// ---------------------------------------------------------------------------
__device__ __forceinline__ float act_elu(float x)  { return x > 0.f ? x : __expf(x) - 1.f; }
__device__ __forceinline__ float act_tanh(float x) {
  float s = __expf(-2.f * fabsf(x));
  float t = (1.f - s) / (1.f + s);
  return x >= 0.f ? t : -t;
}
__device__ __forceinline__ float act_softplus(float x) {
  return fmaxf(x, 0.f) + __logf(1.f + __expf(-fabsf(x)));
}
__device__ __forceinline__ float act_sigmoid(float x) { return 1.f / (1.f + __expf(-x)); }

// ---------------------------------------------------------------------------
// One fused linear layer on a BROWS-row LDS tile. Each wave owns one 16-row
// M-tile (mb) and a 64-col N-slice (wn) of each NSTEP-wide block N-chunk.
// MFMA 16x16x32 f16: A[m=lane&15][k=(lane>>4)*8+j] (LDS), B[k][n]=W[n][k]
// (8 contiguous k per lane from weights), C/D col=lane&15 row=(lane>>4)*4+i.
// ACT: 1=elu->LDS, 2=tanh->LDS, 5=L2 (mu raw / softplus sigma -> LDS+global),
//      6=sigmoid(softplus)->global, 7=softplus->global
// W32=true: emergency path loading int32 weights directly (no d_ws cache).
// ---------------------------------------------------------------------------
template <int ACT, bool W32, int NSTEP>
__device__ __forceinline__ void gemm_layer(
    const f16* __restrict__ Wf, const int* __restrict__ W32p,
    const float* __restrict__ sv, const float* __restrict__ bv,
    int kpad, int opad, int o_real, int k_real,
    const f16* lin, f16* lout, int out_cols,
    float* __restrict__ g0, float* __restrict__ g1, long row0, int gw,
    int mb, int wn, int lrow, int lq) {
  const f16* ap = lin + (mb + lrow) * STRIDE + lq * 8;
#pragma unroll 1
  for (int nc = 0; nc < opad; nc += NSTEP) {
    const int nb = nc + wn * 64;
    if (nb < opad) {
      f32x4 acc[4] = {{0.f,0.f,0.f,0.f},{0.f,0.f,0.f,0.f},{0.f,0.f,0.f,0.f},{0.f,0.f,0.f,0.f}};
      const f16* bp[4];
      const int* b32[4];
#pragma unroll
      for (int t = 0; t < 4; ++t) {
        int n = nb + 16 * t + lrow;
        bp[t] = Wf + (size_t)n * kpad + lq * 8;
        int rn = n < o_real ? n : o_real - 1;     // clamp: garbage rows masked by sc=0
        b32[t] = W32p ? (W32p + (size_t)rn * k_real) : nullptr;
      }
      for (int k = 0; k < kpad; k += 32) {
        f16x8 av = *(const f16x8*)(ap + k);
#pragma unroll
        for (int t = 0; t < 4; ++t) {
          f16x8 bv8;
          if (!W32) {
            bv8 = *(const f16x8*)(bp[t] + k);
          } else {
#pragma unroll
            for (int j = 0; j < 8; ++j) {
              int kk = k + lq * 8 + j;
              bv8[j] = (f16)(float)((kk < k_real) ? b32[t][kk] : 0);
            }
          }
          acc[t] = __builtin_amdgcn_mfma_f32_16x16x32_f16(av, bv8, acc[t], 0, 0, 0);
        }
      }
#pragma unroll
      for (int t = 0; t < 4; ++t) {
        int n = nb + 16 * t + lrow;
        bool nv = n < o_real;
        float sc = nv ? sv[n] * (1.f / 127.f) : 0.f;
        float bb = nv ? bv[n] : 0.f;
#pragma unroll
        for (int i = 0; i < 4; ++i) {
          int m = mb + lq * 4 + i;
          float v = acc[t][i] * sc + bb;
          if (ACT == 1 || ACT == 2) {
            float r = (ACT == 1) ? act_elu(v) : act_tanh(v);
            if (n < out_cols) lout[m * STRIDE + n] = nv ? (f16)r : (f16)0.f;
          } else if (ACT == 5) {
            if (n < 80) {
              g0[(row0 + m) * 80 + n] = v;
              lout[m * STRIDE + n] = (f16)v;
            } else if (n < 160) {
              float sp = act_softplus(v);
              g1[(row0 + m) * 80 + (n - 80)] = sp;
              lout[m * STRIDE + n] = (f16)sp;
            }
          } else if (ACT == 6) {
            if (nv) g0[(row0 + m) * gw + n] = act_sigmoid(act_softplus(v));
          } else if (ACT == 7) {
            if (nv) g0[(row0 + m) * gw + n] = act_softplus(v);
          }
        }
      }
    }
  }
  __syncthreads();
}

// ---------------------------------------------------------------------------
struct FusedArgs {
  const float* x; const float* eps;
  const f16* wf[10];
  const int* w32[10];
  const float* s[10]; const float* b[10];
  float* mlp; float* vae; float* mu; float* sig;
};

// BROWS rows/block; MW = BROWS/16 M-waves; NW N-waves; BLOCK = MW*NW*64 threads.
template <int BROWS, int BLOCK, int MW, int NW, bool W32>
__global__ __launch_bounds__(BLOCK) void fused_kernel(FusedArgs A) {
  extern __shared__ char smem[];
  f16* bufA = (f16*)smem;
  f16* bufB = bufA + BROWS * STRIDE;
  const int tid  = threadIdx.x;
  const int lane = tid & 63;
  const int w    = tid >> 6;
  const int wm   = w % MW, wn = w / MW;
  const int lrow = lane & 15, lq = lane >> 4;
  const int mb   = wm * 16;
  const long row0 = (long)blockIdx.x * BROWS;
  constexpr int NSTEP = NW * 64;

#define GLAYER(ACTV, L, IN, OUT, OUTC, G0, G1, GW) \
  gemm_layer<ACTV, W32, NSTEP>(A.wf[L], W32 ? A.w32[L] : nullptr, A.s[L], A.b[L], \
      LKP[L], LOPD[L], LO[L], LK[L], IN, OUT, OUTC, G0, G1, row0, GW, mb, wn, lrow, lq)

  // stage x (fp32 [B,379]) -> bufA f16, cols 379..383 zeroed
  for (int idx = tid; idx < BROWS * 384; idx += BLOCK) {
    int r = idx / 384, c = idx - r * 384;
    float v = (c < 379) ? A.x[(row0 + r) * 379 + c] : 0.f;
    bufA[r * STRIDE + c] = (f16)v;
  }
  __syncthreads();

  // encoder
  GLAYER(1, 0, bufA, bufB, 608, nullptr, nullptr, 0);
  GLAYER(2, 1, bufB, bufA, 608, nullptr, nullptr, 0);
  GLAYER(5, 2, bufA, bufB, 160, A.mu, A.sig, 0);

  // z = fp16(mu + sigma*eps) -> bufA cols [0,96)
  for (int idx = tid; idx < BROWS * 96; idx += BLOCK) {
    int r = idx / 96, c = idx - r * 96;
    float zv = 0.f;
    if (c < 80) {
      float muv = (float)bufB[r * STRIDE + c];
      float sgv = (float)bufB[r * STRIDE + 80 + c];
      zv = muv + sgv * A.eps[(row0 + r) * 80 + c];
    }
    bufA[r * STRIDE + c] = (f16)zv;
  }
  __syncthreads();

  // m-chain (input bufB cols [0,160) = [mu | softplus(sigma)])
  GLAYER(2, 6, bufB, bufA + 128, 64, nullptr, nullptr, 0);
  GLAYER(1, 7, bufA + 128, bufB, 64, nullptr, nullptr, 0);
  GLAYER(1, 8, bufB, bufA + 192, 64, nullptr, nullptr, 0);
  GLAYER(7, 9, bufA + 192, nullptr, 0, A.mlp, nullptr, 2);

  // d-chain (input z = bufA cols [0,96))
  GLAYER(2, 3, bufA, bufB, 608, nullptr, nullptr, 0);
  GLAYER(1, 4, bufB, bufA, 608, nullptr, nullptr, 0);
  GLAYER(6, 5, bufA, nullptr, 0, A.vae, nullptr, 379);
#undef GLAYER
}

// ---------------------------------------------------------------------------
extern "C" void kernel_launch(void* const* d_in, const int* in_sizes, int n_in,
                              void* d_out, int out_size, void* d_ws, size_t ws_size,
                              hipStream_t stream) {
  (void)in_sizes; (void)n_in; (void)out_size;

  f16* wf = (f16*)d_ws;
  const bool ws_ok = ws_size >= (size_t)WTOTAL * sizeof(f16);

  int dev = 0;
  hipGetDevice(&dev);
  int maxlds = 0;
  hipDeviceGetAttribute(&maxlds, hipDeviceAttributeMaxSharedMemoryPerBlock, dev);

  if (ws_ok) {
    ConvArgs ca;
    for (int l = 0; l < 10; ++l) ca.w[l] = (const int*)d_in[2 + 3 * l];
    ca.dst = wf;
    hipLaunchKernelGGL(convert_weights, dim3(742), dim3(256), 0, stream, ca);  // 742*256*8 == WTOTAL
  }

  FusedArgs fa;
  fa.x   = (const float*)d_in[0];
  fa.eps = (const float*)d_in[1];
  for (int l = 0; l < 10; ++l) {
    fa.wf[l]  = wf + WOFF[l];
    fa.w32[l] = (const int*)d_in[2 + 3 * l];
    fa.s[l]   = (const float*)d_in[3 + 3 * l];
    fa.b[l]   = (const float*)d_in[4 + 3 * l];
  }
  float* out = (float*)d_out;
  fa.mlp = out;                                   // [B,2]
  fa.vae = out + (long)BATCH * 2;                 // [B,379]
  fa.mu  = out + (long)BATCH * (2 + 379);         // [B,80]
  fa.sig = out + (long)BATCH * (2 + 379 + 80);    // [B,80]

  const int ldsA = 2 * 64 * STRIDE * 2;   // 157696
  const int ldsB = 2 * 32 * STRIDE * 2;   //  78848
  const int ldsC = 2 * 16 * STRIDE * 2;   //  39424

  if (ws_ok) {
    if (maxlds >= ldsA) {
      hipFuncSetAttribute(reinterpret_cast<const void*>(&fused_kernel<64,512,4,2,false>),
                          hipFuncAttributeMaxDynamicSharedMemorySize, ldsA);
      hipLaunchKernelGGL((fused_kernel<64,512,4,2,false>), dim3(BATCH/64), dim3(512), ldsA, stream, fa);
    } else if (maxlds >= ldsB) {
      hipFuncSetAttribute(reinterpret_cast<const void*>(&fused_kernel<32,256,2,2,false>),
                          hipFuncAttributeMaxDynamicSharedMemorySize, ldsB);
      hipLaunchKernelGGL((fused_kernel<32,256,2,2,false>), dim3(BATCH/32), dim3(256), ldsB, stream, fa);
    } else {
      hipLaunchKernelGGL((fused_kernel<16,256,1,4,false>), dim3(BATCH/16), dim3(256), ldsC, stream, fa);
    }
  } else {
    if (maxlds >= ldsA) {
      hipFuncSetAttribute(reinterpret_cast<const void*>(&fused_kernel<64,512,4,2,true>),
                          hipFuncAttributeMaxDynamicSharedMemorySize, ldsA);
      hipLaunchKernelGGL((fused_kernel<64,512,4,2,true>), dim3(BATCH/64), dim3(512), ldsA, stream, fa);
    } else if (maxlds >= ldsB) {
      hipFuncSetAttribute(reinterpret_cast<const void*>(&fused_kernel<32,256,2,2,true>),
                          hipFuncAttributeMaxDynamicSharedMemorySize, ldsB);
      hipLaunchKernelGGL((fused_kernel<32,256,2,2,true>), dim3(BATCH/32), dim3(256), ldsB, stream, fa);
    } else {
      hipLaunchKernelGGL((fused_kernel<16,256,1,4,true>), dim3(BATCH/16), dim3(256), ldsC, stream, fa);
    }
  }
}

// Round 4
// 1422.203 us; speedup vs baseline: 1.9177x; 1.9177x over previous
//
#include <hip/hip_runtime.h>
#include <stdint.h>
#include <stddef.h>

typedef _Float16 f16;
typedef f16 f16x8 __attribute__((ext_vector_type(8)));
typedef float f32x4 __attribute__((ext_vector_type(4)));

#define STRIDE 616          // LDS row stride (f16): 1232 B; 308 dwords, 308%32=20 -> spreads banks
#define BATCH 131072

// Per-layer dims: (o, k); kpad = align32(k); opad = align128(o) = T*8*16
static constexpr int  LO[10]  = {600,600,160,600,600,379,40,40,40,2};
static constexpr int  LK[10]  = {379,600,600,80,600,600,160,40,40,40};
static constexpr int  LKP[10] = {384,608,608,96,608,608,160,64,64,64};
static constexpr long WOFF[11] = {0,245760,634880,790528,851968,1241088,1474560,1495040,1503232,1511424,1519616};
#define WTOTAL 1519616      // f16 elems (~2.9 MB in d_ws)

// ---------------------------------------------------------------------------
// Harness delivers integer inputs as int32. int32 [o][k] -> f16 padded
// [opad][kpad], exact integer values; scale/bias applied in fp32 epilogue.
// ---------------------------------------------------------------------------
struct ConvArgs { const int* w[10]; f16* dst; };

__global__ __launch_bounds__(256) void convert_weights(ConvArgs a) {
  long e8 = ((long)blockIdx.x * 256 + threadIdx.x) * 8;
#pragma unroll
  for (int l = 0; l < 10; ++l) {
    if (e8 >= WOFF[l] && e8 < WOFF[l + 1]) {
      int local = (int)(e8 - WOFF[l]);
      int o  = local / LKP[l];
      int k0 = local - o * LKP[l];
      const int* w = a.w[l];
      f16 v8[8];
#pragma unroll
      for (int j = 0; j < 8; ++j) {
        int k = k0 + j;
        int iv = (o < LO[l] && k < LK[l]) ? w[o * LK[l] + k] : 0;
        v8[j] = (f16)(float)iv;
      }
      *(f16x8*)(a.dst + e8) = *(const f16x8*)v8;
    }
  }
}

// ---------------------------------------------------------------------------
__device__ __forceinline__ float act_elu(float x)  { return x > 0.f ? x : __expf(x) - 1.f; }
__device__ __forceinline__ float act_tanh(float x) {
  float s = __expf(-2.f * fabsf(x));
  float t = (1.f - s) / (1.f + s);
  return x >= 0.f ? t : -t;
}
__device__ __forceinline__ float act_softplus(float x) {
  return fmaxf(x, 0.f) + __logf(1.f + __expf(-fabsf(x)));
}
__device__ __forceinline__ float act_sigmoid(float x) { return 1.f / (1.f + __expf(-x)); }

// ---------------------------------------------------------------------------
// One fused linear layer on the 64-row LDS tile, 8 waves.
// Wave w owns N-tiles {w, w+8, ..., w+8(T-1)} (16 cols each) and computes ALL
// four 16-row M-tiles for each: per k-step 4 A-reads (LDS, broadcast across
// waves) + T B-loads (L2) feed 4*T MFMAs -> B-frag reused 4x in registers.
// MFMA 16x16x32 f16: A[m=lane&15][k=(lane>>4)*8+j], B[k][n]=W[n][k] (8
// contiguous k per lane), C/D col=lane&15 row=(lane>>4)*4+i (verified R3).
// ACT: 1=elu->LDS, 2=tanh->LDS, 5=L2 (mu raw / softplus sigma -> LDS+global),
//      6=sigmoid(softplus)->global, 7=softplus->global
// ---------------------------------------------------------------------------
template <int ACT, int T, int KP>
__device__ __forceinline__ void gemm_layer(
    const f16* __restrict__ Wf, const float* __restrict__ sv, const float* __restrict__ bv,
    int o_real,
    const f16* lin, f16* lout, int out_cols,
    float* __restrict__ g0, float* __restrict__ g1, long row0, int gw,
    int w, int lrow, int lq) {
  f32x4 acc[T][4];
#pragma unroll
  for (int t = 0; t < T; ++t)
#pragma unroll
    for (int m = 0; m < 4; ++m) acc[t][m] = (f32x4){0.f, 0.f, 0.f, 0.f};

  const f16* ap = lin + lrow * STRIDE + lq * 8;
  const f16* bp[T];
#pragma unroll
  for (int t = 0; t < T; ++t) {
    int n = (w + 8 * t) * 16 + lrow;
    bp[t] = Wf + (size_t)n * KP + lq * 8;
  }

  for (int k = 0; k < KP; k += 32) {
    f16x8 av[4];
#pragma unroll
    for (int m = 0; m < 4; ++m) av[m] = *(const f16x8*)(ap + m * 16 * STRIDE + k);
    f16x8 bq[T];
#pragma unroll
    for (int t = 0; t < T; ++t) bq[t] = *(const f16x8*)(bp[t] + k);
#pragma unroll
    for (int t = 0; t < T; ++t)
#pragma unroll
      for (int m = 0; m < 4; ++m)
        acc[t][m] = __builtin_amdgcn_mfma_f32_16x16x32_f16(av[m], bq[t], acc[t][m], 0, 0, 0);
  }

#pragma unroll
  for (int t = 0; t < T; ++t) {
    int n = (w + 8 * t) * 16 + lrow;
    bool nv = n < o_real;
    float sc = nv ? sv[n] * (1.f / 127.f) : 0.f;
    float bb = nv ? bv[n] : 0.f;
#pragma unroll
    for (int m = 0; m < 4; ++m) {
#pragma unroll
      for (int i = 0; i < 4; ++i) {
        int row = m * 16 + lq * 4 + i;
        float v = acc[t][m][i] * sc + bb;
        if (ACT == 1 || ACT == 2) {
          float r = (ACT == 1) ? act_elu(v) : act_tanh(v);
          if (n < out_cols) lout[row * STRIDE + n] = nv ? (f16)r : (f16)0.f;
        } else if (ACT == 5) {
          if (n < 80) {
            g0[(row0 + row) * 80 + n] = v;
            lout[row * STRIDE + n] = (f16)v;
          } else if (n < 160) {
            float sp = act_softplus(v);
            g1[(row0 + row) * 80 + (n - 80)] = sp;
            lout[row * STRIDE + n] = (f16)sp;
          }
        } else if (ACT == 6) {
          if (nv) g0[(row0 + row) * gw + n] = act_sigmoid(act_softplus(v));
        } else if (ACT == 7) {
          if (nv) g0[(row0 + row) * gw + n] = act_softplus(v);
        }
      }
    }
  }
  __syncthreads();
}

// ---------------------------------------------------------------------------
struct FusedArgs {
  const float* x; const float* eps;
  const f16* wf[10];
  const float* s[10]; const float* b[10];
  float* mlp; float* vae; float* mu; float* sig;
};

__global__ __launch_bounds__(512) void fused_kernel(FusedArgs A) {
  extern __shared__ char smem[];
  f16* bufA = (f16*)smem;
  f16* bufB = bufA + 64 * STRIDE;
  const int tid  = threadIdx.x;
  const int lane = tid & 63;
  const int w    = tid >> 6;
  const int lrow = lane & 15, lq = lane >> 4;
  const long row0 = (long)blockIdx.x * 64;

#define GLAYER(ACTV, T, L, IN, OUT, OUTC, G0, G1, GW) \
  gemm_layer<ACTV, T, LKP[L]>(A.wf[L], A.s[L], A.b[L], LO[L], \
      IN, OUT, OUTC, G0, G1, row0, GW, w, lrow, lq)

  // stage x (fp32 [B,379]) -> bufA f16, cols 379..383 zeroed
  for (int idx = tid; idx < 64 * 384; idx += 512) {
    int r = idx / 384, c = idx - r * 384;
    float v = (c < 379) ? A.x[(row0 + r) * 379 + c] : 0.f;
    bufA[r * STRIDE + c] = (f16)v;
  }
  __syncthreads();

  // encoder
  GLAYER(1, 5, 0, bufA, bufB, 608, nullptr, nullptr, 0);
  GLAYER(2, 5, 1, bufB, bufA, 608, nullptr, nullptr, 0);
  GLAYER(5, 2, 2, bufA, bufB, 160, A.mu, A.sig, 0);

  // z = fp16(mu + sigma*eps) -> bufA cols [0,96)
  for (int idx = tid; idx < 64 * 96; idx += 512) {
    int r = idx / 96, c = idx - r * 96;
    float zv = 0.f;
    if (c < 80) {
      float muv = (float)bufB[r * STRIDE + c];
      float sgv = (float)bufB[r * STRIDE + 80 + c];
      zv = muv + sgv * A.eps[(row0 + r) * 80 + c];
    }
    bufA[r * STRIDE + c] = (f16)zv;
  }
  __syncthreads();

  // m-chain (input bufB cols [0,160) = [mu | softplus(sigma)])
  GLAYER(2, 1, 6, bufB, bufA + 128, 64, nullptr, nullptr, 0);
  GLAYER(1, 1, 7, bufA + 128, bufB, 64, nullptr, nullptr, 0);
  GLAYER(1, 1, 8, bufB, bufA + 192, 64, nullptr, nullptr, 0);
  GLAYER(7, 1, 9, bufA + 192, nullptr, 0, A.mlp, nullptr, 2);

  // d-chain (input z = bufA cols [0,96))
  GLAYER(2, 5, 3, bufA, bufB, 608, nullptr, nullptr, 0);
  GLAYER(1, 5, 4, bufB, bufA, 608, nullptr, nullptr, 0);
  GLAYER(6, 3, 5, bufA, nullptr, 0, A.vae, nullptr, 379);
#undef GLAYER
}

// ---------------------------------------------------------------------------
extern "C" void kernel_launch(void* const* d_in, const int* in_sizes, int n_in,
                              void* d_out, int out_size, void* d_ws, size_t ws_size,
                              hipStream_t stream) {
  (void)in_sizes; (void)n_in; (void)out_size; (void)ws_size;

  f16* wf = (f16*)d_ws;

  ConvArgs ca;
  for (int l = 0; l < 10; ++l) ca.w[l] = (const int*)d_in[2 + 3 * l];
  ca.dst = wf;
  hipLaunchKernelGGL(convert_weights, dim3(742), dim3(256), 0, stream, ca);  // 742*256*8 == WTOTAL

  FusedArgs fa;
  fa.x   = (const float*)d_in[0];
  fa.eps = (const float*)d_in[1];
  for (int l = 0; l < 10; ++l) {
    fa.wf[l] = wf + WOFF[l];
    fa.s[l]  = (const float*)d_in[3 + 3 * l];
    fa.b[l]  = (const float*)d_in[4 + 3 * l];
  }
  float* out = (float*)d_out;
  fa.mlp = out;                                   // [B,2]
  fa.vae = out + (long)BATCH * 2;                 // [B,379]
  fa.mu  = out + (long)BATCH * (2 + 379);         // [B,80]
  fa.sig = out + (long)BATCH * (2 + 379 + 80);    // [B,80]

  const int lds_bytes = 2 * 64 * STRIDE * 2;      // 157696 B (proven launchable in R3)
  hipFuncSetAttribute(reinterpret_cast<const void*>(fused_kernel),
                      hipFuncAttributeMaxDynamicSharedMemorySize, lds_bytes);
  hipLaunchKernelGGL(fused_kernel, dim3(BATCH / 64), dim3(512), lds_bytes, stream, fa);
}